// Round 5
// baseline (608.212 us; speedup 1.0000x reference)
//
#include <hip/hip_runtime.h>

typedef unsigned short u16;
typedef unsigned int u32;
typedef __bf16 bf16x8 __attribute__((ext_vector_type(8)));
typedef float f32x4 __attribute__((ext_vector_type(4)));
typedef u16 u16x8 __attribute__((ext_vector_type(8)));

#define NTOK 8192
#define CDIM 1024
#define NEXP 8
#define FEDIM 1024
#define FSDIM 4096

#define GLD16(gp, lp) __builtin_amdgcn_global_load_lds( \
    (const __attribute__((address_space(1))) void*)(gp), \
    (__attribute__((address_space(3))) void*)(lp), 16, 0, 0)

__device__ __forceinline__ u16 f2bf(float f) {
  u32 u = __float_as_uint(f);
  u += 0x7FFFu + ((u >> 16) & 1u);   // RNE
  return (u16)(u >> 16);
}

// ---------------- gate: scores, softmax, top-2, expert lists, x->bf16 -------
__global__ __launch_bounds__(256) void gate_kernel(
    const float* __restrict__ x, const float* __restrict__ gw,
    float* __restrict__ scores, u16* __restrict__ xb, int* __restrict__ cnt,
    int* __restrict__ tok, float* __restrict__ wgt)
{
  __shared__ int lcnt[NEXP];
  __shared__ int lbase[NEXP];
  __shared__ int rec_i[32];
  __shared__ int rec_p1[32], rec_p2[32];
  __shared__ float rec_w1[32], rec_w2[32];

  int tid = threadIdx.x, wave = tid >> 6, lane = tid & 63;
  if (tid < NEXP) lcnt[tid] = 0;
  __syncthreads();

  int tbase = blockIdx.x * 32 + wave * 8;
#pragma unroll
  for (int it = 0; it < 8; ++it) {
    int n = tbase + it;
    const float4* xr = (const float4*)(x + (size_t)n * CDIM) + lane * 4;
    float4 xv[4];
#pragma unroll
    for (int j = 0; j < 4; j++) xv[j] = xr[j];
    u16x8 rA, rB;
    rA[0]=f2bf(xv[0].x); rA[1]=f2bf(xv[0].y); rA[2]=f2bf(xv[0].z); rA[3]=f2bf(xv[0].w);
    rA[4]=f2bf(xv[1].x); rA[5]=f2bf(xv[1].y); rA[6]=f2bf(xv[1].z); rA[7]=f2bf(xv[1].w);
    rB[0]=f2bf(xv[2].x); rB[1]=f2bf(xv[2].y); rB[2]=f2bf(xv[2].z); rB[3]=f2bf(xv[2].w);
    rB[4]=f2bf(xv[3].x); rB[5]=f2bf(xv[3].y); rB[6]=f2bf(xv[3].z); rB[7]=f2bf(xv[3].w);
    u16* xrow = xb + (size_t)n * CDIM + lane * 16;
    *(u16x8*)xrow = rA;
    *(u16x8*)(xrow + 8) = rB;

    float s[NEXP];
#pragma unroll
    for (int e = 0; e < NEXP; e++) {
      const float4* g = (const float4*)(gw + (size_t)e * CDIM) + lane * 4;
      float a = 0.f;
#pragma unroll
      for (int j = 0; j < 4; j++) {
        float4 gv = g[j];
        a += xv[j].x * gv.x + xv[j].y * gv.y + xv[j].z * gv.z + xv[j].w * gv.w;
      }
#pragma unroll
      for (int o = 32; o > 0; o >>= 1) a += __shfl_xor(a, o);
      s[e] = a;
    }
    if (lane == 0) {
      float m = s[0];
      for (int e = 1; e < NEXP; e++) m = fmaxf(m, s[e]);
      float p[NEXP], sum = 0.f;
      for (int e = 0; e < NEXP; e++) { p[e] = __expf(s[e] - m); sum += p[e]; }
      int i1 = 0;
      for (int e = 1; e < NEXP; e++) if (p[e] > p[i1]) i1 = e;
      int i2 = (i1 == 0) ? 1 : 0;
      for (int e = 0; e < NEXP; e++) if (e != i1 && p[e] > p[i2]) i2 = e;
      float w1 = p[i1] / sum, w2 = p[i2] / sum;
#pragma unroll
      for (int e = 0; e < NEXP; e++) scores[(size_t)n * NEXP + e] = s[e];
      int p1 = atomicAdd(&lcnt[i1], 1);
      int p2 = atomicAdd(&lcnt[i2], 1);
      int slot = wave * 8 + it;
      rec_i[slot] = i1 | (i2 << 8);
      rec_p1[slot] = p1; rec_p2[slot] = p2;
      rec_w1[slot] = w1; rec_w2[slot] = w2;
    }
  }
  __syncthreads();
  if (tid < NEXP) lbase[tid] = atomicAdd(&cnt[tid], lcnt[tid]);
  __syncthreads();
  if (tid < 32) {
    int n = blockIdx.x * 32 + tid;
    int i1 = rec_i[tid] & 0xff, i2 = rec_i[tid] >> 8;
    int q1 = lbase[i1] + rec_p1[tid];
    int q2 = lbase[i2] + rec_p2[tid];
    tok[i1 * NTOK + q1] = n; wgt[i1 * NTOK + q1] = rec_w1[tid];
    tok[i2 * NTOK + q2] = n; wgt[i2 * NTOK + q2] = rec_w2[tid];
  }
}

__global__ void prefix_kernel(const int* __restrict__ cnt, int* __restrict__ prefix) {
  if (threadIdx.x == 0 && blockIdx.x == 0) {
    int a = 0;
    for (int e = 0; e < NEXP; e++) { prefix[e] = a; a += cnt[e]; }
    prefix[NEXP] = a;
  }
}

// ---------------- tiled transpose f32[R][C] -> bf16[C][R], batched in z ------
__global__ __launch_bounds__(256) void transpose_kernel(const float* __restrict__ src,
    u16* __restrict__ dst, int R, int C)
{
  __shared__ float tile[32][33];
  size_t base = (size_t)blockIdx.z * R * C;
  int c0 = blockIdx.x * 32, r0 = blockIdx.y * 32;
  int tx = threadIdx.x & 31, ty = threadIdx.x >> 5;
#pragma unroll
  for (int i = 0; i < 4; i++) {
    int r = ty + i * 8;
    tile[r][tx] = src[base + (size_t)(r0 + r) * C + c0 + tx];
  }
  __syncthreads();
#pragma unroll
  for (int i = 0; i < 4; i++) {
    int c = ty + i * 8;
    dst[base + (size_t)(c0 + c) * R + r0 + tx] = f2bf(tile[tx][c]);
  }
}

// -------- interleaving transpose: dst[2j]=s1 col j, dst[2j+1]=s2 col j ------
__global__ __launch_bounds__(256) void transpose_i_kernel(
    const float* __restrict__ s1, const float* __restrict__ s2,
    u16* __restrict__ dst, int R, int C, size_t sstride, size_t dstride)
{
  __shared__ float t1[32][33], t2[32][33];
  size_t sbase = (size_t)blockIdx.z * sstride;
  size_t dbase = (size_t)blockIdx.z * dstride;
  int c0 = blockIdx.x * 32, r0 = blockIdx.y * 32;
  int tx = threadIdx.x & 31, ty = threadIdx.x >> 5;
#pragma unroll
  for (int i = 0; i < 4; i++) {
    int r = ty + i * 8;
    t1[r][tx] = s1[sbase + (size_t)(r0 + r) * C + c0 + tx];
    t2[r][tx] = s2[sbase + (size_t)(r0 + r) * C + c0 + tx];
  }
  __syncthreads();
#pragma unroll
  for (int i = 0; i < 4; i++) {
    int c = ty + i * 8;
    dst[dbase + (size_t)(2 * (c0 + c) + 0) * R + r0 + tx] = f2bf(t1[tx][c]);
    dst[dbase + (size_t)(2 * (c0 + c) + 1) * R + r0 + tx] = f2bf(t2[tx][c]);
  }
}

// ================= 256-row tile GEMM, BK=64, 8 waves, counted vmcnt =========
// A bf16 [*, lda] row-major; B in B^T layout [ncols][ldb].
// LDS swizzle (T2, rule #21): linear global_load_lds dest; SOURCE col-chunk
// pre-XORed with row&7; ds_read XORs the slot the same way -> 2-way (free).
// Pipeline (T3/T4): stage t+2 then wait vmcnt(TOTLD) = tile t+1 landed; loads
// stay in flight across one full compute phase. Raw s_barrier (no drain).
// EPI: 0 = SwiGLU pair epilogue (B has W1/W2 interleaved cols; even/odd lane
//          pair exchanged via shfl_xor(1); silu(g)*v -> bf16 H).
//      2 = store f32.  4 = *wgt + atomicAdd scatter to out rows tok[].
// AMODE: 0 direct rows; 1 rows gathered via tok (H compacted at prefix+r);
//        2 rows at prefix[e]+r (compacted A), scatter epilogue rows tok[].
#define BM2 256
#define BK2 64

template<int EPI, int AMODE, int BN_>
__global__ __launch_bounds__(512, 2) void gemm256(
    const u16* __restrict__ A, int lda,
    const u16* __restrict__ B, size_t bstride, int ldb,
    int M, int K,
    u16* __restrict__ Hout, int ldh,
    float* __restrict__ outF, int ldo,
    const int* __restrict__ cnt, const int* __restrict__ prefix,
    const int* __restrict__ tok, const float* __restrict__ wgt)
{
  constexpr int WN = BN_ / 4;        // per-wave col span
  constexpr int N_REP = WN / 16;     // 16-col frags per wave
  constexpr int ACH = 4;             // A stage chunks (64 rows each)
  constexpr int BCH = BN_ / 64;      // B stage chunks

  int e = blockIdx.z;
  int Mloc = (AMODE == 0) ? M : cnt[e];
  int mbase = blockIdx.y * BM2;
  if (AMODE != 0 && mbase >= Mloc) return;
  int nbase = blockIdx.x * BN_;
  int tid = threadIdx.x;
  int lane = tid & 63;
  int wid = tid >> 6;
  int wr = wid >> 2, wc = wid & 3;   // 2 x 4 wave grid
  int fr = lane & 15;

  __shared__ __align__(16) u16 As[2][BM2 * BK2];
  __shared__ __align__(16) u16 Bs[2][BN_ * BK2];

  // ---- staging addressing (linear LDS dest = base + lane*16) ----
  int srow = tid >> 3;                         // 0..63: row within chunk
  int scol = ((tid & 7) ^ (srow & 7)) * 8;     // inverse-swizzled source col
  int pfx = (AMODE == 0) ? 0 : prefix[e];

  size_t arow[ACH];
#pragma unroll
  for (int c = 0; c < ACH; c++) {
    int rloc = mbase + c * 64 + srow;
    if (AMODE == 0)      arow[c] = rloc;
    else if (AMODE == 1) arow[c] = tok[e * NTOK + min(rloc, Mloc - 1)];
    else                 arow[c] = pfx + min(rloc, Mloc - 1);
  }
  const u16* Aps[ACH];
#pragma unroll
  for (int c = 0; c < ACH; c++) Aps[c] = A + arow[c] * (size_t)lda + scol;
  const u16* Bb = B + ((AMODE != 0) ? (size_t)e * bstride : 0);
  const u16* Bps[BCH];
#pragma unroll
  for (int c = 0; c < BCH; c++)
    Bps[c] = Bb + (size_t)(nbase + c * 64 + srow) * ldb + scol;

  auto STAGE = [&](int buf, int kof) {
#pragma unroll
    for (int c = 0; c < ACH; c++) GLD16(Aps[c] + kof, &As[buf][c * 4096 + tid * 8]);
#pragma unroll
    for (int c = 0; c < BCH; c++) GLD16(Bps[c] + kof, &Bs[buf][c * 4096 + tid * 8]);
  };

  f32x4 acc[8][N_REP] = {};

  auto COMPUTE = [&](int buf) {
#pragma unroll
    for (int ks = 0; ks < 2; ks++) {
      int slot = ((((ks << 2) + (lane >> 4)) ^ (fr & 7)) << 3);  // swizzled k-chunk
      const u16* as = &As[buf][(wr * 128 + fr) * BK2 + slot];
      const u16* bs = &Bs[buf][(wc * WN + fr) * BK2 + slot];
      bf16x8 bfr[N_REP];
#pragma unroll
      for (int n = 0; n < N_REP; n++)
        bfr[n] = *(const bf16x8*)&bs[n * 1024];
#pragma unroll
      for (int m = 0; m < 8; m++) {
        bf16x8 af = *(const bf16x8*)&as[m * 1024];
#pragma unroll
        for (int n = 0; n < N_REP; n++)
          acc[m][n] = __builtin_amdgcn_mfma_f32_16x16x32_bf16(af, bfr[n], acc[m][n], 0, 0, 0);
      }
    }
  };

  int nt = K / BK2;
  STAGE(0, 0);
  STAGE(1, BK2);
  if constexpr (ACH + BCH == 8) asm volatile("s_waitcnt vmcnt(8)" ::: "memory");
  else                          asm volatile("s_waitcnt vmcnt(6)" ::: "memory");
  __builtin_amdgcn_s_barrier();
  __builtin_amdgcn_sched_barrier(0);

  for (int t = 0; t < nt; ++t) {
    COMPUTE(t & 1);
    __builtin_amdgcn_sched_barrier(0);
    if (t + 2 < nt) {
      __builtin_amdgcn_s_barrier();          // all waves done reading buf[t&1]
      STAGE(t & 1, (t + 2) * BK2);
      if constexpr (ACH + BCH == 8) asm volatile("s_waitcnt vmcnt(8)" ::: "memory");
      else                          asm volatile("s_waitcnt vmcnt(6)" ::: "memory");
      __builtin_amdgcn_s_barrier();          // tile t+1 visible everywhere
      __builtin_amdgcn_sched_barrier(0);
    } else if (t + 1 < nt) {
      __builtin_amdgcn_s_barrier();
      asm volatile("s_waitcnt vmcnt(0)" ::: "memory");
      __builtin_amdgcn_s_barrier();
      __builtin_amdgcn_sched_barrier(0);
    }
  }

  // ---- epilogue — C/D layout: col = lane&15, row = (lane>>4)*4 + j ----
#pragma unroll
  for (int m = 0; m < 8; m++) {
#pragma unroll
    for (int j = 0; j < 4; j++) {
      int rloc = wr * 128 + m * 16 + (lane >> 4) * 4 + j;
      int rr = mbase + rloc;
      if (AMODE != 0 && rr >= Mloc) continue;
      int tk = 0; float wv = 0.f;
      if (EPI == 4) { tk = tok[e * NTOK + rr]; wv = wgt[e * NTOK + rr]; }
#pragma unroll
      for (int n = 0; n < N_REP; n++) {
        int wcol = wc * WN + n * 16 + fr;
        float v = acc[m][n][j];
        if (EPI == 0) {
          float o = __shfl_xor(v, 1);        // partner holds the other of (g,v)
          float g  = (fr & 1) ? o : v;
          float vv = (fr & 1) ? v : o;
          float hv = (g / (1.f + __expf(-g))) * vv;
          if (!(fr & 1))
            Hout[(size_t)(pfx + rr) * ldh + ((nbase + wcol) >> 1)] = f2bf(hv);
        } else if (EPI == 2) {
          outF[(size_t)rr * ldo + nbase + wcol] = v;
        } else {
          unsafeAtomicAdd(&outF[(size_t)tk * ldo + nbase + wcol], v * wv);
        }
      }
    }
  }
}

// ---------------- host ----------------
extern "C" void kernel_launch(void* const* d_in, const int* in_sizes, int n_in,
                              void* d_out, int out_size, void* d_ws, size_t ws_size,
                              hipStream_t stream)
{
  const float* x   = (const float*)d_in[0];
  const float* gw  = (const float*)d_in[1];
  const float* ew1 = (const float*)d_in[2];
  const float* ew2 = (const float*)d_in[3];
  const float* ewp = (const float*)d_in[4];
  const float* sw1 = (const float*)d_in[5];
  const float* sw2 = (const float*)d_in[6];
  const float* swp = (const float*)d_in[7];
  float* out    = (float*)d_out;
  float* scores = out + (size_t)NTOK * CDIM;

  char* wsp = (char*)d_ws;
  size_t off = 0;
  auto alloc = [&](size_t bytes) -> void* {
    void* p = wsp + off; off += (bytes + 255) & ~(size_t)255; return p;
  };
  u16* xb   = (u16*)alloc((size_t)NTOK * CDIM * 2);
  u16* swi  = (u16*)alloc((size_t)2 * FSDIM * CDIM * 2);          // interleaved shared W1/W2
  u16* ewi  = (u16*)alloc((size_t)NEXP * 2 * FEDIM * CDIM * 2);   // interleaved expert W1/W2
  u16* swpt = (u16*)alloc((size_t)CDIM * FSDIM * 2);
  u16* ewpt = (u16*)alloc((size_t)NEXP * CDIM * FEDIM * 2);
  u16* hs   = (u16*)alloc((size_t)NTOK * FSDIM * 2);              // shared h
  u16* he   = (u16*)alloc((size_t)2 * NTOK * FEDIM * 2);          // expert h (compacted)
  int* cnt  = (int*)alloc(256);
  int* pfx  = (int*)alloc(256);
  int* tok  = (int*)alloc((size_t)NEXP * NTOK * 4);
  float* wgt = (float*)alloc((size_t)NEXP * NTOK * 4);
  if (off > ws_size) return;

  hipMemsetAsync(cnt, 0, 32, stream);
  gate_kernel<<<NTOK / 32, 256, 0, stream>>>(x, gw, scores, xb, cnt, tok, wgt);
  prefix_kernel<<<1, 64, 0, stream>>>(cnt, pfx);
  transpose_i_kernel<<<dim3(FSDIM/32, CDIM/32, 1), 256, 0, stream>>>(
      sw1, sw2, swi, CDIM, FSDIM, 0, 0);
  transpose_i_kernel<<<dim3(FEDIM/32, CDIM/32, NEXP), 256, 0, stream>>>(
      ew1, ew2, ewi, CDIM, FEDIM, (size_t)CDIM * FEDIM, (size_t)2 * FEDIM * CDIM);
  transpose_kernel<<<dim3(CDIM/32, FSDIM/32, 1), 256, 0, stream>>>(swp, swpt, FSDIM, CDIM);
  transpose_kernel<<<dim3(CDIM/32, FEDIM/32, NEXP), 256, 0, stream>>>(ewp, ewpt, FEDIM, CDIM);

  // shared FFN: fused SwiGLU (N_eff = 2*FS = 8192, K=1024) -> hs [8192][4096]
  gemm256<0,0,256><<<dim3(2*FSDIM/256, NTOK/256, 1), 512, 0, stream>>>(
      xb, CDIM, swi, 0, CDIM, NTOK, CDIM, hs, FSDIM, nullptr, 0,
      nullptr, nullptr, nullptr, nullptr);
  // shared proj: [8192][4096] @ [4096][1024] -> out (f32 store)
  gemm256<2,0,128><<<dim3(CDIM/128, NTOK/256, 1), 512, 0, stream>>>(
      hs, FSDIM, swpt, 0, FSDIM, NTOK, FSDIM, nullptr, 0, out, CDIM,
      nullptr, nullptr, nullptr, nullptr);

  // experts: fused SwiGLU on gathered rows (N_eff = 2*FE = 2048) -> he compacted
  gemm256<0,1,256><<<dim3(2*FEDIM/256, NTOK/256, NEXP), 512, 0, stream>>>(
      xb, CDIM, ewi, (size_t)2 * FEDIM * CDIM, CDIM, 0, CDIM, he, FEDIM, nullptr, 0,
      cnt, pfx, tok, nullptr);
  // expert proj: weighted atomic scatter into out
  gemm256<4,2,128><<<dim3(CDIM/128, NTOK/256, NEXP), 512, 0, stream>>>(
      he, FEDIM, ewpt, (size_t)CDIM * FEDIM, FEDIM, 0, FEDIM, nullptr, 0, out, CDIM,
      cnt, pfx, tok, wgt);
}